// Round 3
// baseline (393.332 us; speedup 1.0000x reference)
//
#include <hip/hip_runtime.h>
#include <math.h>

#define DIM 480          // 128*1 + 64*3 + 32*5
#define BLOCK 256
#define EPS 1e-8f

typedef float v4 __attribute__((ext_vector_type(4)));   // native vector: OK for nontemporal builtins

__device__ __forceinline__ float sig(float n) {
    // scaling = silu(max(n,eps))/max(n,eps) == sigmoid(max(n,eps))
    n = fmaxf(n, EPS);
    return __builtin_amdgcn_rcpf(1.0f + __expf(-n));
}

__global__ __launch_bounds__(BLOCK) void norm_act_kernel(
    const float* __restrict__ in, float* __restrict__ out, int n_rows)
{
    const int tid = blockIdx.x * BLOCK + threadIdx.x;
    const int t0 = n_rows * 32;   // R0: 128 floats / 4 per thread
    const int t1 = n_rows * 16;   // R1: 64 groups of 3, 4 groups per thread
    const int t2 = n_rows * 8;    // R2: 32 groups of 5, 4 groups per thread

    if (tid < t0) {
        // ---- region 0: 128 x 0e, elementwise ----
        const int row = tid >> 5, j = tid & 31;
        const size_t off = (size_t)row * DIM + j * 4;
        v4 x = *(const v4*)(in + off);
        x.x *= sig(fabsf(x.x));
        x.y *= sig(fabsf(x.y));
        x.z *= sig(fabsf(x.z));
        x.w *= sig(fabsf(x.w));
        __builtin_nontemporal_store(x, (v4*)(out + off));
    } else if (tid < t0 + t1) {
        // ---- region 1: 64 x 1o (d=3), 4 groups = 12 floats = 3 v4 ----
        const int t = tid - t0;
        const int row = t >> 4, j = t & 15;
        const size_t off = (size_t)row * DIM + 128 + j * 12;
        v4 a = *(const v4*)(in + off);
        v4 b = *(const v4*)(in + off + 4);
        v4 c = *(const v4*)(in + off + 8);
        // groups: (a.x,a.y,a.z) (a.w,b.x,b.y) (b.z,b.w,c.x) (c.y,c.z,c.w)
        const float s0 = sig(sqrtf(a.x*a.x + a.y*a.y + a.z*a.z));
        const float s1 = sig(sqrtf(a.w*a.w + b.x*b.x + b.y*b.y));
        const float s2 = sig(sqrtf(b.z*b.z + b.w*b.w + c.x*c.x));
        const float s3 = sig(sqrtf(c.y*c.y + c.z*c.z + c.w*c.w));
        a.x *= s0; a.y *= s0; a.z *= s0;
        a.w *= s1; b.x *= s1; b.y *= s1;
        b.z *= s2; b.w *= s2; c.x *= s2;
        c.y *= s3; c.z *= s3; c.w *= s3;
        __builtin_nontemporal_store(a, (v4*)(out + off));
        __builtin_nontemporal_store(b, (v4*)(out + off + 4));
        __builtin_nontemporal_store(c, (v4*)(out + off + 8));
    } else if (tid < t0 + t1 + t2) {
        // ---- region 2: 32 x 2e (d=5), 4 groups = 20 floats = 5 v4 ----
        const int t = tid - t0 - t1;
        const int row = t >> 3, j = t & 7;
        const size_t off = (size_t)row * DIM + 320 + j * 20;
        v4 a = *(const v4*)(in + off);
        v4 b = *(const v4*)(in + off + 4);
        v4 c = *(const v4*)(in + off + 8);
        v4 d = *(const v4*)(in + off + 12);
        v4 e = *(const v4*)(in + off + 16);
        // groups: (a.xyzw,b.x) (b.yzw,c.xy) (c.zw,d.xyz) (d.w,e.xyzw)
        const float s0 = sig(sqrtf(a.x*a.x + a.y*a.y + a.z*a.z + a.w*a.w + b.x*b.x));
        const float s1 = sig(sqrtf(b.y*b.y + b.z*b.z + b.w*b.w + c.x*c.x + c.y*c.y));
        const float s2 = sig(sqrtf(c.z*c.z + c.w*c.w + d.x*d.x + d.y*d.y + d.z*d.z));
        const float s3 = sig(sqrtf(d.w*d.w + e.x*e.x + e.y*e.y + e.z*e.z + e.w*e.w));
        a.x *= s0; a.y *= s0; a.z *= s0; a.w *= s0; b.x *= s0;
        b.y *= s1; b.z *= s1; b.w *= s1; c.x *= s1; c.y *= s1;
        c.z *= s2; c.w *= s2; d.x *= s2; d.y *= s2; d.z *= s2;
        d.w *= s3; e.x *= s3; e.y *= s3; e.z *= s3; e.w *= s3;
        __builtin_nontemporal_store(a, (v4*)(out + off));
        __builtin_nontemporal_store(b, (v4*)(out + off + 4));
        __builtin_nontemporal_store(c, (v4*)(out + off + 8));
        __builtin_nontemporal_store(d, (v4*)(out + off + 12));
        __builtin_nontemporal_store(e, (v4*)(out + off + 16));
    }
}

extern "C" void kernel_launch(void* const* d_in, const int* in_sizes, int n_in,
                              void* d_out, int out_size, void* d_ws, size_t ws_size,
                              hipStream_t stream) {
    const float* in  = (const float*)d_in[0];
    float*       out = (float*)d_out;
    const int n_rows  = in_sizes[0] / DIM;          // 100000
    const int threads = n_rows * (32 + 16 + 8);     // 5.6M
    const int grid    = (threads + BLOCK - 1) / BLOCK;
    norm_act_kernel<<<grid, BLOCK, 0, stream>>>(in, out, n_rows);
}